// Round 1
// baseline (11138.284 us; speedup 1.0000x reference)
//
#include <hip/hip_runtime.h>
#include <hip/hip_bf16.h>
#include <math.h>

// ---------------------------------------------------------------------------
// MPNN node classifier, fp32 baseline.
// msg = relu(X@W+b) computed per-node (not per-edge); conv = scatter-add of
// msg[src] into h[dst]; self loops folded into h-init (D2D copy of msg).
// ---------------------------------------------------------------------------

#define F_DIM 256   // F_IN == H == 256
#define C_DIM 40

// --- 64x64x16 register-tiled SGEMM, C[M x 256] = act(A[M x 256] @ W[256 x 256] + b)
__global__ __launch_bounds__(256, 2) void gemm256(
    const float* __restrict__ A, const float* __restrict__ W,
    const float* __restrict__ bias, float* __restrict__ out,
    int M, int reluIn, int reluOut)
{
    constexpr int K = 256, NCOL = 256;
    __shared__ float As[16][64];   // [k][m]
    __shared__ float Bs[16][64];   // [k][n]
    const int tid  = threadIdx.x;
    const int row0 = blockIdx.x * 64;
    const int col0 = blockIdx.y * 64;

    const int aRow = tid >> 2;          // 0..63
    const int aCol = (tid & 3) << 2;    // 0,4,8,12
    const int bRow = tid >> 4;          // 0..15
    const int bCol = (tid & 15) << 2;   // 0..60

    const int tr = (tid >> 4) << 2;     // thread row in tile
    const int tc = (tid & 15) << 2;     // thread col in tile

    float acc[4][4] = {};

    const int gr = row0 + aRow;
    const float* Aptr = A + (size_t)gr * K + aCol;
    const float* Wptr = W + (size_t)bRow * NCOL + col0 + bCol;

    for (int k0 = 0; k0 < K; k0 += 16) {
        float4 av = make_float4(0.f, 0.f, 0.f, 0.f);
        if (gr < M) av = *(const float4*)(Aptr + k0);
        if (reluIn) {
            av.x = fmaxf(av.x, 0.f); av.y = fmaxf(av.y, 0.f);
            av.z = fmaxf(av.z, 0.f); av.w = fmaxf(av.w, 0.f);
        }
        const float4 bv = *(const float4*)(Wptr + (size_t)k0 * NCOL);
        As[aCol + 0][aRow] = av.x;
        As[aCol + 1][aRow] = av.y;
        As[aCol + 2][aRow] = av.z;
        As[aCol + 3][aRow] = av.w;
        *(float4*)&Bs[bRow][bCol] = bv;
        __syncthreads();
        #pragma unroll
        for (int k = 0; k < 16; ++k) {
            const float4 a4 = *(const float4*)&As[k][tr];
            const float4 b4 = *(const float4*)&Bs[k][tc];
            const float am[4] = {a4.x, a4.y, a4.z, a4.w};
            const float bn[4] = {b4.x, b4.y, b4.z, b4.w};
            #pragma unroll
            for (int i = 0; i < 4; ++i)
                #pragma unroll
                for (int j = 0; j < 4; ++j)
                    acc[i][j] += am[i] * bn[j];
        }
        __syncthreads();
    }

    const float4 b4 = *(const float4*)(bias + col0 + tc);
    const float bb[4] = {b4.x, b4.y, b4.z, b4.w};
    #pragma unroll
    for (int i = 0; i < 4; ++i) {
        const int orow = row0 + tr + i;
        if (orow < M) {
            float4 v;
            float vv[4];
            #pragma unroll
            for (int j = 0; j < 4; ++j) {
                vv[j] = acc[i][j] + bb[j];
                if (reluOut) vv[j] = fmaxf(vv[j], 0.f);
            }
            v.x = vv[0]; v.y = vv[1]; v.z = vv[2]; v.w = vv[3];
            *(float4*)(out + (size_t)orow * NCOL + col0 + tc) = v;
        }
    }
}

// --- edge scatter: h[dst] += msg[src], one wave per edge, float4 per lane
__global__ __launch_bounds__(256) void edge_scatter(
    const float* __restrict__ msg, const int* __restrict__ src,
    const int* __restrict__ dst, float* __restrict__ h, int nE)
{
    const int wid  = (blockIdx.x * 256 + threadIdx.x) >> 6;
    const int lane = threadIdx.x & 63;
    if (wid >= nE) return;
    const int s = src[wid];
    const int d = dst[wid];
    const float4 v = ((const float4*)(msg + (size_t)s * F_DIM))[lane];
    float* hp = h + (size_t)d * F_DIM + lane * 4;
    atomicAdd(hp + 0, v.x);
    atomicAdd(hp + 1, v.y);
    atomicAdd(hp + 2, v.z);
    atomicAdd(hp + 3, v.w);
}

// --- FC: logits[i][c] = sum_k relu(h[i][k]) * wfc[k][c] + bfc[c]; wave/row
__global__ __launch_bounds__(256) void fc40(
    const float* __restrict__ h, const float* __restrict__ wfc,
    const float* __restrict__ bfc, float* __restrict__ logits, int M)
{
    const int row  = (blockIdx.x * 256 + threadIdx.x) >> 6;
    const int lane = threadIdx.x & 63;
    if (row >= M || lane >= C_DIM) return;
    const float* hr = h + (size_t)row * F_DIM;
    float acc = 0.f;
    #pragma unroll 4
    for (int k = 0; k < F_DIM; ++k) {
        const float hv = fmaxf(hr[k], 0.f);
        acc += hv * wfc[(size_t)k * C_DIM + lane];
    }
    logits[(size_t)row * C_DIM + lane] = acc + bfc[lane];
}

// --- sparse PvT: out[prow[i]] += pval[i] * logits[pcol[i]], wave/nnz
__global__ __launch_bounds__(256) void pvt_scatter(
    const float* __restrict__ logits, const int* __restrict__ prow,
    const int* __restrict__ pcol, const float* __restrict__ pval,
    float* __restrict__ out, int nnz)
{
    const int i    = (blockIdx.x * 256 + threadIdx.x) >> 6;
    const int lane = threadIdx.x & 63;
    if (i >= nnz || lane >= C_DIM) return;
    const int r = prow[i];
    const int c = pcol[i];
    const float v = pval[i];
    atomicAdd(out + (size_t)r * C_DIM + lane, v * logits[(size_t)c * C_DIM + lane]);
}

// --- row-wise log_softmax in place, wave/row (lanes 0..39 active)
__global__ __launch_bounds__(256) void log_softmax40(float* __restrict__ out, int M)
{
    const int row  = (blockIdx.x * 256 + threadIdx.x) >> 6;
    const int lane = threadIdx.x & 63;
    if (row >= M) return;
    const float v = (lane < C_DIM) ? out[(size_t)row * C_DIM + lane] : -INFINITY;
    float m = v;
    #pragma unroll
    for (int off = 32; off >= 1; off >>= 1)
        m = fmaxf(m, __shfl_xor(m, off, 64));
    float e = (lane < C_DIM) ? expf(v - m) : 0.f;
    float s = e;
    #pragma unroll
    for (int off = 32; off >= 1; off >>= 1)
        s += __shfl_xor(s, off, 64);
    if (lane < C_DIM)
        out[(size_t)row * C_DIM + lane] = v - m - logf(s);
}

extern "C" void kernel_launch(void* const* d_in, const int* in_sizes, int n_in,
                              void* d_out, int out_size, void* d_ws, size_t ws_size,
                              hipStream_t stream)
{
    const float* x        = (const float*)d_in[0];
    const int*   edge_src = (const int*)d_in[1];
    const int*   edge_dst = (const int*)d_in[2];
    const int*   pvt_row  = (const int*)d_in[3];
    const int*   pvt_col  = (const int*)d_in[4];
    const float* pvt_val  = (const float*)d_in[5];
    const float* w1       = (const float*)d_in[6];
    const float* b1       = (const float*)d_in[7];
    const float* w2       = (const float*)d_in[8];
    const float* b2       = (const float*)d_in[9];
    const float* wfc      = (const float*)d_in[10];
    const float* bfc      = (const float*)d_in[11];

    const int N   = in_sizes[0] / F_DIM;   // 50000
    const int E   = in_sizes[1];           // 1600000
    const int NNZ = in_sizes[3];           // 50000

    float* out = (float*)d_out;

    // workspace layout
    const size_t nodeElems = (size_t)N * F_DIM;
    float* bufA   = (float*)d_ws;                 // msg buffer
    float* bufB   = bufA + nodeElems;             // h buffer
    float* logits = bufB + nodeElems;             // N x 40

    const size_t nodeBytes = nodeElems * sizeof(float);

    const dim3 gemmGrid((N + 63) / 64, 4);
    const int scatterBlocks = (E + 3) / 4;        // 4 waves (edges) per block
    const int rowBlocks     = (N + 3) / 4;
    const int nnzBlocks     = (NNZ + 3) / 4;

    // --- layer 1: msg1 = relu(X@W1+b1)
    gemm256<<<gemmGrid, 256, 0, stream>>>(x, w1, b1, bufA, N, 0, 1);
    // h1 := msg1 (self loops), then h1[dst] += msg1[src]
    hipMemcpyAsync(bufB, bufA, nodeBytes, hipMemcpyDeviceToDevice, stream);
    edge_scatter<<<scatterBlocks, 256, 0, stream>>>(bufA, edge_src, edge_dst, bufB, E);

    // --- layer 2: msg2 = relu(relu(h1)@W2+b2)   (reluIn folds post-agg relu)
    gemm256<<<gemmGrid, 256, 0, stream>>>(bufB, w2, b2, bufA, N, 1, 1);
    hipMemcpyAsync(bufB, bufA, nodeBytes, hipMemcpyDeviceToDevice, stream);
    edge_scatter<<<scatterBlocks, 256, 0, stream>>>(bufA, edge_src, edge_dst, bufB, E);

    // --- FC: logits = relu(h2) @ wfc + bfc
    fc40<<<rowBlocks, 256, 0, stream>>>(bufB, wfc, bfc, logits, N);

    // --- PvT scatter into d_out, then log_softmax
    hipMemsetAsync(d_out, 0, (size_t)N * C_DIM * sizeof(float), stream);
    pvt_scatter<<<nnzBlocks, 256, 0, stream>>>(logits, pvt_row, pvt_col, pvt_val, out, NNZ);
    log_softmax40<<<rowBlocks, 256, 0, stream>>>(out, N);
}

// Round 2
// 1190.081 us; speedup vs baseline: 9.3593x; 9.3593x over previous
//
#include <hip/hip_runtime.h>
#include <hip/hip_bf16.h>
#include <math.h>

// ---------------------------------------------------------------------------
// MPNN node classifier.
// R1: replace atomic edge_scatter (6.55 GB atomic write traffic, 5.3ms each)
// with per-call CSR build + register-accumulating gather (one wave per dst
// node, h row written exactly once). Self-loop folded into accumulator init.
// ---------------------------------------------------------------------------

#define F_DIM 256   // F_IN == H == 256
#define C_DIM 40

// --- 64x64x16 register-tiled SGEMM, C[M x 256] = act(A[M x 256] @ W[256 x 256] + b)
__global__ __launch_bounds__(256, 2) void gemm256(
    const float* __restrict__ A, const float* __restrict__ W,
    const float* __restrict__ bias, float* __restrict__ out,
    int M, int reluIn, int reluOut)
{
    constexpr int K = 256, NCOL = 256;
    __shared__ float As[16][64];   // [k][m]
    __shared__ float Bs[16][64];   // [k][n]
    const int tid  = threadIdx.x;
    const int row0 = blockIdx.x * 64;
    const int col0 = blockIdx.y * 64;

    const int aRow = tid >> 2;          // 0..63
    const int aCol = (tid & 3) << 2;    // 0,4,8,12
    const int bRow = tid >> 4;          // 0..15
    const int bCol = (tid & 15) << 2;   // 0..60

    const int tr = (tid >> 4) << 2;     // thread row in tile
    const int tc = (tid & 15) << 2;     // thread col in tile

    float acc[4][4] = {};

    const int gr = row0 + aRow;
    const float* Aptr = A + (size_t)gr * K + aCol;
    const float* Wptr = W + (size_t)bRow * NCOL + col0 + bCol;

    for (int k0 = 0; k0 < K; k0 += 16) {
        float4 av = make_float4(0.f, 0.f, 0.f, 0.f);
        if (gr < M) av = *(const float4*)(Aptr + k0);
        if (reluIn) {
            av.x = fmaxf(av.x, 0.f); av.y = fmaxf(av.y, 0.f);
            av.z = fmaxf(av.z, 0.f); av.w = fmaxf(av.w, 0.f);
        }
        const float4 bv = *(const float4*)(Wptr + (size_t)k0 * NCOL);
        As[aCol + 0][aRow] = av.x;
        As[aCol + 1][aRow] = av.y;
        As[aCol + 2][aRow] = av.z;
        As[aCol + 3][aRow] = av.w;
        *(float4*)&Bs[bRow][bCol] = bv;
        __syncthreads();
        #pragma unroll
        for (int k = 0; k < 16; ++k) {
            const float4 a4 = *(const float4*)&As[k][tr];
            const float4 b4 = *(const float4*)&Bs[k][tc];
            const float am[4] = {a4.x, a4.y, a4.z, a4.w};
            const float bn[4] = {b4.x, b4.y, b4.z, b4.w};
            #pragma unroll
            for (int i = 0; i < 4; ++i)
                #pragma unroll
                for (int j = 0; j < 4; ++j)
                    acc[i][j] += am[i] * bn[j];
        }
        __syncthreads();
    }

    const float4 b4 = *(const float4*)(bias + col0 + tc);
    const float bb[4] = {b4.x, b4.y, b4.z, b4.w};
    #pragma unroll
    for (int i = 0; i < 4; ++i) {
        const int orow = row0 + tr + i;
        if (orow < M) {
            float4 v;
            float vv[4];
            #pragma unroll
            for (int j = 0; j < 4; ++j) {
                vv[j] = acc[i][j] + bb[j];
                if (reluOut) vv[j] = fmaxf(vv[j], 0.f);
            }
            v.x = vv[0]; v.y = vv[1]; v.z = vv[2]; v.w = vv[3];
            *(float4*)(out + (size_t)orow * NCOL + col0 + tc) = v;
        }
    }
}

// --- CSR build step 1: degree histogram over dst
__global__ __launch_bounds__(256) void count_deg(
    const int* __restrict__ dst, int* __restrict__ deg, int E)
{
    const int i = blockIdx.x * 256 + threadIdx.x;
    if (i < E) atomicAdd(&deg[dst[i]], 1);
}

// --- CSR build step 2: exclusive scan (single workgroup, 1024 threads)
__global__ __launch_bounds__(1024) void scan_deg(
    const int* __restrict__ deg, int* __restrict__ rowptr, int N)
{
    __shared__ int waveSums[16];
    __shared__ int carrySh;
    const int tid  = threadIdx.x;
    const int lane = tid & 63;
    const int wid  = tid >> 6;
    if (tid == 0) carrySh = 0;
    __syncthreads();
    for (int base = 0; base < N; base += 1024) {
        const int i = base + tid;
        const int v = (i < N) ? deg[i] : 0;
        // inclusive wave scan
        int s = v;
        #pragma unroll
        for (int off = 1; off < 64; off <<= 1) {
            const int t = __shfl_up(s, off, 64);
            if (lane >= off) s += t;
        }
        if (lane == 63) waveSums[wid] = s;
        __syncthreads();
        if (wid == 0) {
            const int ws = (lane < 16) ? waveSums[lane] : 0;
            int ss = ws;
            #pragma unroll
            for (int off = 1; off < 16; off <<= 1) {
                const int t = __shfl_up(ss, off, 64);
                if (lane >= off) ss += t;
            }
            if (lane < 16) waveSums[lane] = ss - ws;   // exclusive
        }
        __syncthreads();
        const int carry = carrySh;
        if (i < N) rowptr[i] = carry + waveSums[wid] + s - v;
        __syncthreads();
        if (tid == 1023) carrySh = carry + waveSums[15] + s;
        __syncthreads();
    }
    if (tid == 0) rowptr[N] = carrySh;
}

// --- CSR build step 3: scatter src ids into buckets (cursor = copy of rowptr)
__global__ __launch_bounds__(256) void fill_csr(
    const int* __restrict__ src, const int* __restrict__ dst,
    int* __restrict__ cursor, int* __restrict__ csr_src, int E)
{
    const int i = blockIdx.x * 256 + threadIdx.x;
    if (i >= E) return;
    const int pos = atomicAdd(&cursor[dst[i]], 1);
    csr_src[pos] = src[i];
}

// --- conv aggregate: h[row] = msg[row] + sum_{e in in-edges(row)} msg[src[e]]
//     one wave per row; float4 per lane; batched src-id loads via shuffle
__global__ __launch_bounds__(256) void csr_gather(
    const float* __restrict__ msg, const int* __restrict__ rowptr,
    const int* __restrict__ csr_src, float* __restrict__ h, int N)
{
    const int row  = (blockIdx.x * 256 + threadIdx.x) >> 6;
    const int lane = threadIdx.x & 63;
    if (row >= N) return;
    const int beg = rowptr[row];
    const int end = rowptr[row + 1];
    float4 acc = ((const float4*)(msg + (size_t)row * F_DIM))[lane];  // self loop
    for (int e0 = beg; e0 < end; e0 += 64) {
        const int n  = min(64, end - e0);
        const int sv = (e0 + lane < end) ? csr_src[e0 + lane] : 0;
        for (int j = 0; j < n; ++j) {
            const int s = __shfl(sv, j, 64);
            const float4 v = ((const float4*)(msg + (size_t)s * F_DIM))[lane];
            acc.x += v.x; acc.y += v.y; acc.z += v.z; acc.w += v.w;
        }
    }
    ((float4*)(h + (size_t)row * F_DIM))[lane] = acc;
}

// --- FC: logits[i][c] = sum_k relu(h[i][k]) * wfc[k][c] + bfc[c]; wave/row
__global__ __launch_bounds__(256) void fc40(
    const float* __restrict__ h, const float* __restrict__ wfc,
    const float* __restrict__ bfc, float* __restrict__ logits, int M)
{
    const int row  = (blockIdx.x * 256 + threadIdx.x) >> 6;
    const int lane = threadIdx.x & 63;
    if (row >= M || lane >= C_DIM) return;
    const float* hr = h + (size_t)row * F_DIM;
    float acc = 0.f;
    #pragma unroll 4
    for (int k = 0; k < F_DIM; ++k) {
        const float hv = fmaxf(hr[k], 0.f);
        acc += hv * wfc[(size_t)k * C_DIM + lane];
    }
    logits[(size_t)row * C_DIM + lane] = acc + bfc[lane];
}

// --- sparse PvT: out[prow[i]] += pval[i] * logits[pcol[i]], wave/nnz
__global__ __launch_bounds__(256) void pvt_scatter(
    const float* __restrict__ logits, const int* __restrict__ prow,
    const int* __restrict__ pcol, const float* __restrict__ pval,
    float* __restrict__ out, int nnz)
{
    const int i    = (blockIdx.x * 256 + threadIdx.x) >> 6;
    const int lane = threadIdx.x & 63;
    if (i >= nnz || lane >= C_DIM) return;
    const int r = prow[i];
    const int c = pcol[i];
    const float v = pval[i];
    atomicAdd(out + (size_t)r * C_DIM + lane, v * logits[(size_t)c * C_DIM + lane]);
}

// --- row-wise log_softmax in place, wave/row (lanes 0..39 active)
__global__ __launch_bounds__(256) void log_softmax40(float* __restrict__ out, int M)
{
    const int row  = (blockIdx.x * 256 + threadIdx.x) >> 6;
    const int lane = threadIdx.x & 63;
    if (row >= M) return;
    const float v = (lane < C_DIM) ? out[(size_t)row * C_DIM + lane] : -INFINITY;
    float m = v;
    #pragma unroll
    for (int off = 32; off >= 1; off >>= 1)
        m = fmaxf(m, __shfl_xor(m, off, 64));
    float e = (lane < C_DIM) ? expf(v - m) : 0.f;
    float s = e;
    #pragma unroll
    for (int off = 32; off >= 1; off >>= 1)
        s += __shfl_xor(s, off, 64);
    if (lane < C_DIM)
        out[(size_t)row * C_DIM + lane] = v - m - logf(s);
}

extern "C" void kernel_launch(void* const* d_in, const int* in_sizes, int n_in,
                              void* d_out, int out_size, void* d_ws, size_t ws_size,
                              hipStream_t stream)
{
    const float* x        = (const float*)d_in[0];
    const int*   edge_src = (const int*)d_in[1];
    const int*   edge_dst = (const int*)d_in[2];
    const int*   pvt_row  = (const int*)d_in[3];
    const int*   pvt_col  = (const int*)d_in[4];
    const float* pvt_val  = (const float*)d_in[5];
    const float* w1       = (const float*)d_in[6];
    const float* b1       = (const float*)d_in[7];
    const float* w2       = (const float*)d_in[8];
    const float* b2       = (const float*)d_in[9];
    const float* wfc      = (const float*)d_in[10];
    const float* bfc      = (const float*)d_in[11];

    const int N   = in_sizes[0] / F_DIM;   // 50000
    const int E   = in_sizes[1];           // 1600000
    const int NNZ = in_sizes[3];           // 50000

    float* out = (float*)d_out;

    // workspace layout (floats/ints interleaved; everything 16B aligned)
    const size_t nodeElems = (size_t)N * F_DIM;
    float* bufA    = (float*)d_ws;                    // msg buffer   (N*256 f32)
    float* bufB    = bufA + nodeElems;                // h buffer     (N*256 f32)
    float* logits  = bufB + nodeElems;                // N x 40 f32
    int*   deg     = (int*)(logits + (size_t)N * C_DIM);
    int*   rowptr  = deg + N;                         // N+1 ints
    int*   cursor  = rowptr + N + 4;                  // N ints
    int*   csr_src = cursor + N + 4;                  // E ints

    const dim3 gemmGrid((N + 63) / 64, 4);
    const int eBlocks   = (E + 255) / 256;
    const int rowBlocks = (N + 3) / 4;
    const int nnzBlocks = (NNZ + 3) / 4;

    // === CSR build (depends only on edge_dst/src) ===
    hipMemsetAsync(deg, 0, (size_t)N * sizeof(int), stream);
    count_deg<<<eBlocks, 256, 0, stream>>>(edge_dst, deg, E);
    scan_deg<<<1, 1024, 0, stream>>>(deg, rowptr, N);
    hipMemcpyAsync(cursor, rowptr, (size_t)N * sizeof(int),
                   hipMemcpyDeviceToDevice, stream);
    fill_csr<<<eBlocks, 256, 0, stream>>>(edge_src, edge_dst, cursor, csr_src, E);

    // === layer 1: msg1 = relu(X@W1+b1); h1 = gather(msg1) ===
    gemm256<<<gemmGrid, 256, 0, stream>>>(x, w1, b1, bufA, N, 0, 1);
    csr_gather<<<rowBlocks, 256, 0, stream>>>(bufA, rowptr, csr_src, bufB, N);

    // === layer 2: msg2 = relu(relu(h1)@W2+b2); h2 = gather(msg2) ===
    gemm256<<<gemmGrid, 256, 0, stream>>>(bufB, w2, b2, bufA, N, 1, 1);
    csr_gather<<<rowBlocks, 256, 0, stream>>>(bufA, rowptr, csr_src, bufB, N);

    // === FC: logits = relu(h2) @ wfc + bfc ===
    fc40<<<rowBlocks, 256, 0, stream>>>(bufB, wfc, bfc, logits, N);

    // === PvT scatter into d_out, then log_softmax ===
    hipMemsetAsync(d_out, 0, (size_t)N * C_DIM * sizeof(float), stream);
    pvt_scatter<<<nnzBlocks, 256, 0, stream>>>(logits, pvt_row, pvt_col, pvt_val, out, NNZ);
    log_softmax40<<<rowBlocks, 256, 0, stream>>>(out, N);
}

// Round 3
// 884.822 us; speedup vs baseline: 12.5882x; 1.3450x over previous
//
#include <hip/hip_runtime.h>
#include <hip/hip_bf16.h>
#include <math.h>

// ---------------------------------------------------------------------------
// MPNN node classifier.
// R2: fp16 storage for msg/h (halves gather traffic) + MFMA fp16 GEMMs
// (fp32 accumulate). CSR gather (R1) unchanged except fp16 rows.
// ---------------------------------------------------------------------------

#define F_DIM 256   // F_IN == H == 256
#define C_DIM 40

typedef _Float16 half8 __attribute__((ext_vector_type(8)));
typedef _Float16 half4 __attribute__((ext_vector_type(4)));
typedef float    f32x4 __attribute__((ext_vector_type(4)));

// --- convert fp32 -> fp16, 4 elements per thread
__global__ __launch_bounds__(256) void cvt_x(
    const float* __restrict__ x, _Float16* __restrict__ xh, int n4)
{
    const int i = blockIdx.x * 256 + threadIdx.x;
    if (i >= n4) return;
    const float4 v = ((const float4*)x)[i];
    half4 h;
    h[0] = (_Float16)v.x; h[1] = (_Float16)v.y;
    h[2] = (_Float16)v.z; h[3] = (_Float16)v.w;
    ((half4*)xh)[i] = h;
}

// --- convert + transpose weight: w[k][n] fp32 -> wt[n][k] fp16  (256x256)
__global__ __launch_bounds__(256) void cvt_wT(
    const float* __restrict__ w, _Float16* __restrict__ wt)
{
    const int n = threadIdx.x;
    const int k = blockIdx.x;
    wt[n * 256 + k] = (_Float16)w[k * 256 + n];
}

// --- MFMA fp16 GEMM: out[M x 256] = f16(relu(A[M x 256] @ Wt^T + bias))
//     A fp16 row-major [m][k]; Wt fp16 [n][k]; block tile 128x64, 4 waves,
//     each wave 32 rows x 64 cols = 2x4 mfma_f32_16x16x32_f16 tiles.
__global__ __launch_bounds__(256, 2) void gemm_f16(
    const _Float16* __restrict__ A, const _Float16* __restrict__ Wt,
    const float* __restrict__ bias, _Float16* __restrict__ out, int M)
{
    constexpr int K = 256;
    constexpr int LDA = 40;                 // padded fp16 stride (80 B): 2-way-free banks
    __shared__ _Float16 As[128 * LDA];
    __shared__ _Float16 Bs[64 * LDA];

    const int tid  = threadIdx.x;
    const int wave = tid >> 6;
    const int lane = tid & 63;
    const int quad = lane >> 4;
    const int l16  = lane & 15;
    const int row0 = blockIdx.x * 128;
    const int col0 = blockIdx.y * 64;

    f32x4 acc[2][4] = {};

    for (int k0 = 0; k0 < K; k0 += 32) {
        // stage A tile: 128 rows x 32 k = 512 chunks of 8 fp16; 2 chunks/thread
        #pragma unroll
        for (int c = tid; c < 512; c += 256) {
            const int r  = c >> 2;
            const int ko = (c & 3) * 8;
            const int gr = row0 + r;
            half8 v = {};
            if (gr < M) v = *(const half8*)(A + (size_t)gr * K + k0 + ko);
            *(half8*)&As[r * LDA + ko] = v;
        }
        // stage B tile: 64 rows(n) x 32 k = 256 chunks; 1 chunk/thread
        {
            const int n  = tid >> 2;
            const int ko = (tid & 3) * 8;
            const half8 v = *(const half8*)(Wt + (size_t)(col0 + n) * K + k0 + ko);
            *(half8*)&Bs[n * LDA + ko] = v;
        }
        __syncthreads();

        half8 af[2], bf[4];
        #pragma unroll
        for (int mi = 0; mi < 2; ++mi)
            af[mi] = *(const half8*)&As[(wave * 32 + mi * 16 + l16) * LDA + quad * 8];
        #pragma unroll
        for (int ni = 0; ni < 4; ++ni)
            bf[ni] = *(const half8*)&Bs[(ni * 16 + l16) * LDA + quad * 8];
        #pragma unroll
        for (int mi = 0; mi < 2; ++mi)
            #pragma unroll
            for (int ni = 0; ni < 4; ++ni)
                acc[mi][ni] = __builtin_amdgcn_mfma_f32_16x16x32_f16(
                    af[mi], bf[ni], acc[mi][ni], 0, 0, 0);
        __syncthreads();
    }

    // epilogue: C/D layout col=lane&15, row=quad*4+reg
    #pragma unroll
    for (int ni = 0; ni < 4; ++ni) {
        const int col = col0 + ni * 16 + l16;
        const float b = bias[col];
        #pragma unroll
        for (int mi = 0; mi < 2; ++mi) {
            #pragma unroll
            for (int r = 0; r < 4; ++r) {
                const int grow = row0 + wave * 32 + mi * 16 + quad * 4 + r;
                if (grow < M) {
                    const float v = fmaxf(acc[mi][ni][r] + b, 0.f);
                    out[(size_t)grow * K + col] = (_Float16)v;
                }
            }
        }
    }
}

// --- CSR build step 1: degree histogram over dst
__global__ __launch_bounds__(256) void count_deg(
    const int* __restrict__ dst, int* __restrict__ deg, int E)
{
    const int i = blockIdx.x * 256 + threadIdx.x;
    if (i < E) atomicAdd(&deg[dst[i]], 1);
}

// --- CSR build step 2: exclusive scan (single workgroup, 1024 threads)
__global__ __launch_bounds__(1024) void scan_deg(
    const int* __restrict__ deg, int* __restrict__ rowptr, int N)
{
    __shared__ int waveSums[16];
    __shared__ int carrySh;
    const int tid  = threadIdx.x;
    const int lane = tid & 63;
    const int wid  = tid >> 6;
    if (tid == 0) carrySh = 0;
    __syncthreads();
    for (int base = 0; base < N; base += 1024) {
        const int i = base + tid;
        const int v = (i < N) ? deg[i] : 0;
        int s = v;
        #pragma unroll
        for (int off = 1; off < 64; off <<= 1) {
            const int t = __shfl_up(s, off, 64);
            if (lane >= off) s += t;
        }
        if (lane == 63) waveSums[wid] = s;
        __syncthreads();
        if (wid == 0) {
            const int ws = (lane < 16) ? waveSums[lane] : 0;
            int ss = ws;
            #pragma unroll
            for (int off = 1; off < 16; off <<= 1) {
                const int t = __shfl_up(ss, off, 64);
                if (lane >= off) ss += t;
            }
            if (lane < 16) waveSums[lane] = ss - ws;   // exclusive
        }
        __syncthreads();
        const int carry = carrySh;
        if (i < N) rowptr[i] = carry + waveSums[wid] + s - v;
        __syncthreads();
        if (tid == 1023) carrySh = carry + waveSums[15] + s;
        __syncthreads();
    }
    if (tid == 0) rowptr[N] = carrySh;
}

// --- CSR build step 3: scatter src ids into buckets (cursor = copy of rowptr)
__global__ __launch_bounds__(256) void fill_csr(
    const int* __restrict__ src, const int* __restrict__ dst,
    int* __restrict__ cursor, int* __restrict__ csr_src, int E)
{
    const int i = blockIdx.x * 256 + threadIdx.x;
    if (i >= E) return;
    const int pos = atomicAdd(&cursor[dst[i]], 1);
    csr_src[pos] = src[i];
}

// --- conv aggregate (fp16 rows, fp32 accumulate, relu on output):
//     h[row] = f16(relu(msg[row] + sum_{in-edges} msg[src]))
__global__ __launch_bounds__(256) void csr_gather_f16(
    const _Float16* __restrict__ msg, const int* __restrict__ rowptr,
    const int* __restrict__ csr_src, _Float16* __restrict__ h, int N)
{
    const int row  = (blockIdx.x * 256 + threadIdx.x) >> 6;
    const int lane = threadIdx.x & 63;
    if (row >= N) return;
    const int beg = rowptr[row];
    const int end = rowptr[row + 1];
    const half4 self = ((const half4*)(msg + (size_t)row * F_DIM))[lane];
    float a0 = (float)self[0], a1 = (float)self[1];
    float a2 = (float)self[2], a3 = (float)self[3];
    for (int e0 = beg; e0 < end; e0 += 64) {
        const int n  = min(64, end - e0);
        const int sv = (e0 + lane < end) ? csr_src[e0 + lane] : 0;
        for (int j = 0; j < n; ++j) {
            const int s = __shfl(sv, j, 64);
            const half4 v = ((const half4*)(msg + (size_t)s * F_DIM))[lane];
            a0 += (float)v[0]; a1 += (float)v[1];
            a2 += (float)v[2]; a3 += (float)v[3];
        }
    }
    half4 o;
    o[0] = (_Float16)fmaxf(a0, 0.f);
    o[1] = (_Float16)fmaxf(a1, 0.f);
    o[2] = (_Float16)fmaxf(a2, 0.f);
    o[3] = (_Float16)fmaxf(a3, 0.f);
    ((half4*)(h + (size_t)row * F_DIM))[lane] = o;
}

// --- FC: logits[i][c] = sum_k h[i][k] * wfc[k][c] + bfc[c]; wave/row
//     (h already relu'd by the gather)
__global__ __launch_bounds__(256) void fc40(
    const _Float16* __restrict__ h, const float* __restrict__ wfc,
    const float* __restrict__ bfc, float* __restrict__ logits, int M)
{
    const int row  = (blockIdx.x * 256 + threadIdx.x) >> 6;
    const int lane = threadIdx.x & 63;
    if (row >= M || lane >= C_DIM) return;
    const _Float16* hr = h + (size_t)row * F_DIM;
    float acc = 0.f;
    #pragma unroll 4
    for (int k = 0; k < F_DIM; ++k)
        acc += (float)hr[k] * wfc[(size_t)k * C_DIM + lane];
    logits[(size_t)row * C_DIM + lane] = acc + bfc[lane];
}

// --- sparse PvT: out[prow[i]] += pval[i] * logits[pcol[i]], wave/nnz
__global__ __launch_bounds__(256) void pvt_scatter(
    const float* __restrict__ logits, const int* __restrict__ prow,
    const int* __restrict__ pcol, const float* __restrict__ pval,
    float* __restrict__ out, int nnz)
{
    const int i    = (blockIdx.x * 256 + threadIdx.x) >> 6;
    const int lane = threadIdx.x & 63;
    if (i >= nnz || lane >= C_DIM) return;
    const int r = prow[i];
    const int c = pcol[i];
    const float v = pval[i];
    atomicAdd(out + (size_t)r * C_DIM + lane, v * logits[(size_t)c * C_DIM + lane]);
}

// --- row-wise log_softmax in place, wave/row (lanes 0..39 active)
__global__ __launch_bounds__(256) void log_softmax40(float* __restrict__ out, int M)
{
    const int row  = (blockIdx.x * 256 + threadIdx.x) >> 6;
    const int lane = threadIdx.x & 63;
    if (row >= M) return;
    const float v = (lane < C_DIM) ? out[(size_t)row * C_DIM + lane] : -INFINITY;
    float m = v;
    #pragma unroll
    for (int off = 32; off >= 1; off >>= 1)
        m = fmaxf(m, __shfl_xor(m, off, 64));
    float e = (lane < C_DIM) ? expf(v - m) : 0.f;
    float s = e;
    #pragma unroll
    for (int off = 32; off >= 1; off >>= 1)
        s += __shfl_xor(s, off, 64);
    if (lane < C_DIM)
        out[(size_t)row * C_DIM + lane] = v - m - logf(s);
}

extern "C" void kernel_launch(void* const* d_in, const int* in_sizes, int n_in,
                              void* d_out, int out_size, void* d_ws, size_t ws_size,
                              hipStream_t stream)
{
    const float* x        = (const float*)d_in[0];
    const int*   edge_src = (const int*)d_in[1];
    const int*   edge_dst = (const int*)d_in[2];
    const int*   pvt_row  = (const int*)d_in[3];
    const int*   pvt_col  = (const int*)d_in[4];
    const float* pvt_val  = (const float*)d_in[5];
    const float* w1       = (const float*)d_in[6];
    const float* b1       = (const float*)d_in[7];
    const float* w2       = (const float*)d_in[8];
    const float* b2       = (const float*)d_in[9];
    const float* wfc      = (const float*)d_in[10];
    const float* bfc      = (const float*)d_in[11];

    const int N   = in_sizes[0] / F_DIM;   // 50000
    const int E   = in_sizes[1];           // 1600000
    const int NNZ = in_sizes[3];           // 50000

    float* out = (float*)d_out;

    // workspace layout
    const size_t nodeElems = (size_t)N * F_DIM;
    _Float16* xh     = (_Float16*)d_ws;               // N*256 fp16
    _Float16* w1t    = xh + nodeElems;                // 256*256 fp16
    _Float16* w2t    = w1t + 65536;                   // 256*256 fp16
    _Float16* bufM   = w2t + 65536;                   // msg, N*256 fp16
    _Float16* bufH   = bufM + nodeElems;              // h,   N*256 fp16
    float*    logits = (float*)(bufH + nodeElems);    // N x 40 f32
    int*      deg    = (int*)(logits + (size_t)N * C_DIM);
    int*      rowptr = deg + N;                       // N+1 ints
    int*      cursor = rowptr + N + 4;                // N ints
    int*      csr_src= cursor + N + 4;                // E ints

    const dim3 gemmGrid((N + 127) / 128, 4);
    const int eBlocks   = (E + 255) / 256;
    const int rowBlocks = (N + 3) / 4;
    const int nnzBlocks = (NNZ + 3) / 4;
    const int x4Blocks  = ((int)(nodeElems / 4) + 255) / 256;

    // === prep: fp16 conversions ===
    cvt_x<<<x4Blocks, 256, 0, stream>>>(x, xh, (int)(nodeElems / 4));
    cvt_wT<<<256, 256, 0, stream>>>(w1, w1t);
    cvt_wT<<<256, 256, 0, stream>>>(w2, w2t);

    // === CSR build ===
    hipMemsetAsync(deg, 0, (size_t)N * sizeof(int), stream);
    count_deg<<<eBlocks, 256, 0, stream>>>(edge_dst, deg, E);
    scan_deg<<<1, 1024, 0, stream>>>(deg, rowptr, N);
    hipMemcpyAsync(cursor, rowptr, (size_t)N * sizeof(int),
                   hipMemcpyDeviceToDevice, stream);
    fill_csr<<<eBlocks, 256, 0, stream>>>(edge_src, edge_dst, cursor, csr_src, E);

    // === layer 1 ===
    gemm_f16<<<gemmGrid, 256, 0, stream>>>(xh, w1t, b1, bufM, N);
    csr_gather_f16<<<rowBlocks, 256, 0, stream>>>(bufM, rowptr, csr_src, bufH, N);

    // === layer 2 ===
    gemm_f16<<<gemmGrid, 256, 0, stream>>>(bufH, w2t, b2, bufM, N);
    csr_gather_f16<<<rowBlocks, 256, 0, stream>>>(bufM, rowptr, csr_src, bufH, N);

    // === FC ===
    fc40<<<rowBlocks, 256, 0, stream>>>(bufH, wfc, bfc, logits, N);

    // === PvT scatter into d_out, then log_softmax ===
    hipMemsetAsync(d_out, 0, (size_t)N * C_DIM * sizeof(float), stream);
    pvt_scatter<<<nnzBlocks, 256, 0, stream>>>(logits, pvt_row, pvt_col, pvt_val, out, NNZ);
    log_softmax40<<<rowBlocks, 256, 0, stream>>>(out, N);
}

// Round 4
// 704.591 us; speedup vs baseline: 15.8082x; 1.2558x over previous
//
#include <hip/hip_runtime.h>
#include <hip/hip_bf16.h>
#include <math.h>

// ---------------------------------------------------------------------------
// MPNN node classifier.
// R3: (a) fc40 latency-bound scalar loop (202us) -> MFMA FC with LDS-resident
// padded weight [48][256] fp16 (~15us expected). (b) layer-1 GEMM stages fp32
// x directly (kills cvt_x + 77MB round trip).
// ---------------------------------------------------------------------------

#define F_DIM 256   // F_IN == H == 256
#define C_DIM 40

typedef _Float16 half8 __attribute__((ext_vector_type(8)));
typedef _Float16 half4 __attribute__((ext_vector_type(4)));
typedef float    f32x4 __attribute__((ext_vector_type(4)));

// --- convert + transpose weight: w[k][n] fp32 -> wt[n][k] fp16  (256x256)
__global__ __launch_bounds__(256) void cvt_wT(
    const float* __restrict__ w, _Float16* __restrict__ wt)
{
    const int n = threadIdx.x;
    const int k = blockIdx.x;
    wt[n * 256 + k] = (_Float16)w[k * 256 + n];
}

// --- convert + transpose + pad FC weight: wfc[k][40] fp32 -> wt[48][256] fp16
__global__ __launch_bounds__(48) void cvt_wfc(
    const float* __restrict__ wfc, _Float16* __restrict__ wt)
{
    const int n = threadIdx.x;   // 0..47
    const int k = blockIdx.x;    // 0..255
    wt[n * 256 + k] = (n < C_DIM) ? (_Float16)wfc[k * C_DIM + n] : (_Float16)0.f;
}

// --- MFMA fp16 GEMM: out[M x 256] = f16(relu(A[M x 256] @ Wt^T + bias))
//     A row-major [m][k] (fp32 if AF32 else fp16); Wt fp16 [n][k];
//     block tile 128x64, 4 waves, each wave 32x64 = 2x4 mfma_f32_16x16x32_f16.
template <bool AF32>
__global__ __launch_bounds__(256, 2) void gemm_f16(
    const void* __restrict__ Av, const _Float16* __restrict__ Wt,
    const float* __restrict__ bias, _Float16* __restrict__ out, int M)
{
    constexpr int K = 256;
    constexpr int LDA = 40;                 // padded fp16 stride: 2-way-free banks
    __shared__ _Float16 As[128 * LDA];
    __shared__ _Float16 Bs[64 * LDA];

    const int tid  = threadIdx.x;
    const int wave = tid >> 6;
    const int lane = tid & 63;
    const int quad = lane >> 4;
    const int l16  = lane & 15;
    const int row0 = blockIdx.x * 128;
    const int col0 = blockIdx.y * 64;

    f32x4 acc[2][4] = {};

    for (int k0 = 0; k0 < K; k0 += 32) {
        // stage A tile: 128 rows x 32 k = 512 chunks of 8 elems; 2 chunks/thread
        #pragma unroll
        for (int c = tid; c < 512; c += 256) {
            const int r  = c >> 2;
            const int ko = (c & 3) * 8;
            const int gr = row0 + r;
            half8 v = {};
            if (gr < M) {
                if constexpr (AF32) {
                    const float* A = (const float*)Av;
                    const float4 u0 = *(const float4*)(A + (size_t)gr * K + k0 + ko);
                    const float4 u1 = *(const float4*)(A + (size_t)gr * K + k0 + ko + 4);
                    v[0] = (_Float16)u0.x; v[1] = (_Float16)u0.y;
                    v[2] = (_Float16)u0.z; v[3] = (_Float16)u0.w;
                    v[4] = (_Float16)u1.x; v[5] = (_Float16)u1.y;
                    v[6] = (_Float16)u1.z; v[7] = (_Float16)u1.w;
                } else {
                    const _Float16* A = (const _Float16*)Av;
                    v = *(const half8*)(A + (size_t)gr * K + k0 + ko);
                }
            }
            *(half8*)&As[r * LDA + ko] = v;
        }
        // stage B tile: 64 rows(n) x 32 k = 256 chunks; 1 chunk/thread
        {
            const int n  = tid >> 2;
            const int ko = (tid & 3) * 8;
            const half8 v = *(const half8*)(Wt + (size_t)(col0 + n) * K + k0 + ko);
            *(half8*)&Bs[n * LDA + ko] = v;
        }
        __syncthreads();

        half8 af[2], bf[4];
        #pragma unroll
        for (int mi = 0; mi < 2; ++mi)
            af[mi] = *(const half8*)&As[(wave * 32 + mi * 16 + l16) * LDA + quad * 8];
        #pragma unroll
        for (int ni = 0; ni < 4; ++ni)
            bf[ni] = *(const half8*)&Bs[(ni * 16 + l16) * LDA + quad * 8];
        #pragma unroll
        for (int mi = 0; mi < 2; ++mi)
            #pragma unroll
            for (int ni = 0; ni < 4; ++ni)
                acc[mi][ni] = __builtin_amdgcn_mfma_f32_16x16x32_f16(
                    af[mi], bf[ni], acc[mi][ni], 0, 0, 0);
        __syncthreads();
    }

    // epilogue: C/D layout col=lane&15, row=quad*4+reg
    #pragma unroll
    for (int ni = 0; ni < 4; ++ni) {
        const int col = col0 + ni * 16 + l16;
        const float b = bias[col];
        #pragma unroll
        for (int mi = 0; mi < 2; ++mi) {
            #pragma unroll
            for (int r = 0; r < 4; ++r) {
                const int grow = row0 + wave * 32 + mi * 16 + quad * 4 + r;
                if (grow < M) {
                    const float v = fmaxf(acc[mi][ni][r] + b, 0.f);
                    out[(size_t)grow * K + col] = (_Float16)v;
                }
            }
        }
    }
}

// --- MFMA FC: logits[M x 40] = h[M x 256] @ wfcT^T + bfc  (no relu)
//     WfcT fp16 [48][256] staged once in LDS; 128-row blocks, 4 waves,
//     each wave 32 rows x 48 cols = 2x3 mfma tiles.
__global__ __launch_bounds__(256, 2) void fc_mfma(
    const _Float16* __restrict__ h, const _Float16* __restrict__ WfcT,
    const float* __restrict__ bfc, float* __restrict__ logits, int M)
{
    constexpr int K = 256;
    constexpr int LDA = 40;
    constexpr int LDB = 264;                // 528 B stride: 16B-aligned, 2-way-free
    __shared__ _Float16 As[128 * LDA];
    __shared__ _Float16 Bs[48 * LDB];

    const int tid  = threadIdx.x;
    const int wave = tid >> 6;
    const int lane = tid & 63;
    const int quad = lane >> 4;
    const int l16  = lane & 15;
    const int row0 = blockIdx.x * 128;

    // stage full WfcT: 48 x 256 fp16 = 1536 half8 chunks, 6/thread
    #pragma unroll
    for (int c = tid; c < 1536; c += 256) {
        const int n  = c >> 5;
        const int ko = (c & 31) * 8;
        *(half8*)&Bs[n * LDB + ko] = *(const half8*)(WfcT + (size_t)n * K + ko);
    }

    f32x4 acc[2][3] = {};

    for (int k0 = 0; k0 < K; k0 += 32) {
        #pragma unroll
        for (int c = tid; c < 512; c += 256) {
            const int r  = c >> 2;
            const int ko = (c & 3) * 8;
            const int gr = row0 + r;
            half8 v = {};
            if (gr < M) v = *(const half8*)(h + (size_t)gr * K + k0 + ko);
            *(half8*)&As[r * LDA + ko] = v;
        }
        __syncthreads();

        half8 af[2], bf[3];
        #pragma unroll
        for (int mi = 0; mi < 2; ++mi)
            af[mi] = *(const half8*)&As[(wave * 32 + mi * 16 + l16) * LDA + quad * 8];
        #pragma unroll
        for (int ni = 0; ni < 3; ++ni)
            bf[ni] = *(const half8*)&Bs[(ni * 16 + l16) * LDB + k0 + quad * 8];
        #pragma unroll
        for (int mi = 0; mi < 2; ++mi)
            #pragma unroll
            for (int ni = 0; ni < 3; ++ni)
                acc[mi][ni] = __builtin_amdgcn_mfma_f32_16x16x32_f16(
                    af[mi], bf[ni], acc[mi][ni], 0, 0, 0);
        __syncthreads();
    }

    #pragma unroll
    for (int ni = 0; ni < 3; ++ni) {
        const int col = ni * 16 + l16;
        if (col >= C_DIM) continue;
        const float b = bfc[col];
        #pragma unroll
        for (int mi = 0; mi < 2; ++mi) {
            #pragma unroll
            for (int r = 0; r < 4; ++r) {
                const int grow = row0 + wave * 32 + mi * 16 + quad * 4 + r;
                if (grow < M)
                    logits[(size_t)grow * C_DIM + col] = acc[mi][ni][r] + b;
            }
        }
    }
}

// --- CSR build step 1: degree histogram over dst
__global__ __launch_bounds__(256) void count_deg(
    const int* __restrict__ dst, int* __restrict__ deg, int E)
{
    const int i = blockIdx.x * 256 + threadIdx.x;
    if (i < E) atomicAdd(&deg[dst[i]], 1);
}

// --- CSR build step 2: exclusive scan (single workgroup, 1024 threads)
__global__ __launch_bounds__(1024) void scan_deg(
    const int* __restrict__ deg, int* __restrict__ rowptr, int N)
{
    __shared__ int waveSums[16];
    __shared__ int carrySh;
    const int tid  = threadIdx.x;
    const int lane = tid & 63;
    const int wid  = tid >> 6;
    if (tid == 0) carrySh = 0;
    __syncthreads();
    for (int base = 0; base < N; base += 1024) {
        const int i = base + tid;
        const int v = (i < N) ? deg[i] : 0;
        int s = v;
        #pragma unroll
        for (int off = 1; off < 64; off <<= 1) {
            const int t = __shfl_up(s, off, 64);
            if (lane >= off) s += t;
        }
        if (lane == 63) waveSums[wid] = s;
        __syncthreads();
        if (wid == 0) {
            const int ws = (lane < 16) ? waveSums[lane] : 0;
            int ss = ws;
            #pragma unroll
            for (int off = 1; off < 16; off <<= 1) {
                const int t = __shfl_up(ss, off, 64);
                if (lane >= off) ss += t;
            }
            if (lane < 16) waveSums[lane] = ss - ws;   // exclusive
        }
        __syncthreads();
        const int carry = carrySh;
        if (i < N) rowptr[i] = carry + waveSums[wid] + s - v;
        __syncthreads();
        if (tid == 1023) carrySh = carry + waveSums[15] + s;
        __syncthreads();
    }
    if (tid == 0) rowptr[N] = carrySh;
}

// --- CSR build step 3: scatter src ids into buckets (cursor = copy of rowptr)
__global__ __launch_bounds__(256) void fill_csr(
    const int* __restrict__ src, const int* __restrict__ dst,
    int* __restrict__ cursor, int* __restrict__ csr_src, int E)
{
    const int i = blockIdx.x * 256 + threadIdx.x;
    if (i >= E) return;
    const int pos = atomicAdd(&cursor[dst[i]], 1);
    csr_src[pos] = src[i];
}

// --- conv aggregate (fp16 rows, fp32 accumulate, relu on output):
//     h[row] = f16(relu(msg[row] + sum_{in-edges} msg[src]))
__global__ __launch_bounds__(256) void csr_gather_f16(
    const _Float16* __restrict__ msg, const int* __restrict__ rowptr,
    const int* __restrict__ csr_src, _Float16* __restrict__ h, int N)
{
    const int row  = (blockIdx.x * 256 + threadIdx.x) >> 6;
    const int lane = threadIdx.x & 63;
    if (row >= N) return;
    const int beg = rowptr[row];
    const int end = rowptr[row + 1];
    const half4 self = ((const half4*)(msg + (size_t)row * F_DIM))[lane];
    float a0 = (float)self[0], a1 = (float)self[1];
    float a2 = (float)self[2], a3 = (float)self[3];
    for (int e0 = beg; e0 < end; e0 += 64) {
        const int n  = min(64, end - e0);
        const int sv = (e0 + lane < end) ? csr_src[e0 + lane] : 0;
        for (int j = 0; j < n; ++j) {
            const int s = __shfl(sv, j, 64);
            const half4 v = ((const half4*)(msg + (size_t)s * F_DIM))[lane];
            a0 += (float)v[0]; a1 += (float)v[1];
            a2 += (float)v[2]; a3 += (float)v[3];
        }
    }
    half4 o;
    o[0] = (_Float16)fmaxf(a0, 0.f);
    o[1] = (_Float16)fmaxf(a1, 0.f);
    o[2] = (_Float16)fmaxf(a2, 0.f);
    o[3] = (_Float16)fmaxf(a3, 0.f);
    ((half4*)(h + (size_t)row * F_DIM))[lane] = o;
}

// --- sparse PvT: out[prow[i]] += pval[i] * logits[pcol[i]], wave/nnz
__global__ __launch_bounds__(256) void pvt_scatter(
    const float* __restrict__ logits, const int* __restrict__ prow,
    const int* __restrict__ pcol, const float* __restrict__ pval,
    float* __restrict__ out, int nnz)
{
    const int i    = (blockIdx.x * 256 + threadIdx.x) >> 6;
    const int lane = threadIdx.x & 63;
    if (i >= nnz || lane >= C_DIM) return;
    const int r = prow[i];
    const int c = pcol[i];
    const float v = pval[i];
    atomicAdd(out + (size_t)r * C_DIM + lane, v * logits[(size_t)c * C_DIM + lane]);
}

// --- row-wise log_softmax in place, wave/row (lanes 0..39 active)
__global__ __launch_bounds__(256) void log_softmax40(float* __restrict__ out, int M)
{
    const int row  = (blockIdx.x * 256 + threadIdx.x) >> 6;
    const int lane = threadIdx.x & 63;
    if (row >= M) return;
    const float v = (lane < C_DIM) ? out[(size_t)row * C_DIM + lane] : -INFINITY;
    float m = v;
    #pragma unroll
    for (int off = 32; off >= 1; off >>= 1)
        m = fmaxf(m, __shfl_xor(m, off, 64));
    float e = (lane < C_DIM) ? expf(v - m) : 0.f;
    float s = e;
    #pragma unroll
    for (int off = 32; off >= 1; off >>= 1)
        s += __shfl_xor(s, off, 64);
    if (lane < C_DIM)
        out[(size_t)row * C_DIM + lane] = v - m - logf(s);
}

extern "C" void kernel_launch(void* const* d_in, const int* in_sizes, int n_in,
                              void* d_out, int out_size, void* d_ws, size_t ws_size,
                              hipStream_t stream)
{
    const float* x        = (const float*)d_in[0];
    const int*   edge_src = (const int*)d_in[1];
    const int*   edge_dst = (const int*)d_in[2];
    const int*   pvt_row  = (const int*)d_in[3];
    const int*   pvt_col  = (const int*)d_in[4];
    const float* pvt_val  = (const float*)d_in[5];
    const float* w1       = (const float*)d_in[6];
    const float* b1       = (const float*)d_in[7];
    const float* w2       = (const float*)d_in[8];
    const float* b2       = (const float*)d_in[9];
    const float* wfc      = (const float*)d_in[10];
    const float* bfc      = (const float*)d_in[11];

    const int N   = in_sizes[0] / F_DIM;   // 50000
    const int E   = in_sizes[1];           // 1600000
    const int NNZ = in_sizes[3];           // 50000

    float* out = (float*)d_out;

    // workspace layout
    const size_t nodeElems = (size_t)N * F_DIM;
    _Float16* w1t    = (_Float16*)d_ws;               // 256*256 fp16
    _Float16* w2t    = w1t + 65536;                   // 256*256 fp16
    _Float16* wfcT   = w2t + 65536;                   // 48*256 fp16
    _Float16* bufM   = wfcT + 48 * 256;               // msg, N*256 fp16
    _Float16* bufH   = bufM + nodeElems;              // h,   N*256 fp16
    float*    logits = (float*)(bufH + nodeElems);    // N x 40 f32
    int*      deg    = (int*)(logits + (size_t)N * C_DIM);
    int*      rowptr = deg + N;                       // N+1 ints
    int*      cursor = rowptr + N + 4;                // N ints
    int*      csr_src= cursor + N + 4;                // E ints

    const dim3 gemmGrid((N + 127) / 128, 4);
    const int fcBlocks  = (N + 127) / 128;
    const int eBlocks   = (E + 255) / 256;
    const int rowBlocks = (N + 3) / 4;
    const int nnzBlocks = (NNZ + 3) / 4;

    // === prep: weight conversions ===
    cvt_wT<<<256, 256, 0, stream>>>(w1, w1t);
    cvt_wT<<<256, 256, 0, stream>>>(w2, w2t);
    cvt_wfc<<<256, 48, 0, stream>>>(wfc, wfcT);

    // === CSR build ===
    hipMemsetAsync(deg, 0, (size_t)N * sizeof(int), stream);
    count_deg<<<eBlocks, 256, 0, stream>>>(edge_dst, deg, E);
    scan_deg<<<1, 1024, 0, stream>>>(deg, rowptr, N);
    hipMemcpyAsync(cursor, rowptr, (size_t)N * sizeof(int),
                   hipMemcpyDeviceToDevice, stream);
    fill_csr<<<eBlocks, 256, 0, stream>>>(edge_src, edge_dst, cursor, csr_src, E);

    // === layer 1 (A = fp32 x, converted in staging) ===
    gemm_f16<true><<<gemmGrid, 256, 0, stream>>>(x, w1t, b1, bufM, N);
    csr_gather_f16<<<rowBlocks, 256, 0, stream>>>(bufM, rowptr, csr_src, bufH, N);

    // === layer 2 ===
    gemm_f16<false><<<gemmGrid, 256, 0, stream>>>(bufH, w2t, b2, bufM, N);
    csr_gather_f16<<<rowBlocks, 256, 0, stream>>>(bufM, rowptr, csr_src, bufH, N);

    // === FC (MFMA) ===
    fc_mfma<<<fcBlocks, 256, 0, stream>>>(bufH, wfcT, bfc, logits, N);

    // === PvT scatter into d_out, then log_softmax ===
    hipMemsetAsync(d_out, 0, (size_t)N * C_DIM * sizeof(float), stream);
    pvt_scatter<<<nnzBlocks, 256, 0, stream>>>(logits, pvt_row, pvt_col, pvt_val, out, NNZ);
    log_softmax40<<<rowBlocks, 256, 0, stream>>>(out, N);
}